// Round 13
// baseline (332.371 us; speedup 1.0000x reference)
//
#include <hip/hip_runtime.h>
#include <hip/hip_bf16.h>
#include <cstdint>
#include <cstddef>

typedef __bf16 bf16;
typedef __bf16 bf16x8 __attribute__((ext_vector_type(8)));
typedef float  f32x4  __attribute__((ext_vector_type(4)));
typedef unsigned short u16x4 __attribute__((ext_vector_type(4)));
typedef uint32_t u32x4 __attribute__((ext_vector_type(4)));

static constexpr int D_MODEL = 1024;
static constexpr int HEADS   = 16;
static constexpr int D_KH    = 64;
static constexpr int D_FF    = 4096;
static constexpr int BATCH   = 4;
static constexpr int SEQ     = 2048;
static constexpr int MROWS   = BATCH * SEQ;  // 8192
static constexpr float QSCALE = 0.18033688011f;  // (1/sqrt(64)) * log2(e)

#define VMCNT(n) asm volatile("s_waitcnt vmcnt(" #n ")" ::: "memory")
#define LGKM0()                                            \
  do {                                                     \
    asm volatile("s_waitcnt lgkmcnt(0)" ::: "memory");     \
    __builtin_amdgcn_sched_barrier(0);                     \
  } while (0)

__device__ __forceinline__ unsigned short bfbits(float f) {
  return __builtin_bit_cast(unsigned short, (bf16)f);
}
__device__ __forceinline__ float bf2f(unsigned short u) {
  return __builtin_bit_cast(float, (uint32_t)u << 16);
}
__device__ __forceinline__ float bf2f_hi(uint32_t w) {
  return __builtin_bit_cast(float, w & 0xffff0000u);
}
__device__ __forceinline__ float bf2f_lo(uint32_t w) {
  return __builtin_bit_cast(float, w << 16);
}
// raw HW exp2 (inputs bounded; no denormal fixup needed)
__device__ __forceinline__ float exp2_raw(float x) {
  float r;
  asm("v_exp_f32 %0, %1" : "=v"(r) : "v"(x));
  return r;
}

__device__ __forceinline__ void gload_lds16(const void* g, void* l) {
  __builtin_amdgcn_global_load_lds(
      (__attribute__((address_space(1))) uint32_t*)(uintptr_t)g,
      (__attribute__((address_space(3))) uint32_t*)(uintptr_t)l, 16, 0, 0);
}

// -------- one prep kernel: x cast (0..4095), mask flags (4096),
//          all weight transposes (4097..7168), vectorized both sides ----
struct PrepArgs {
  const float* x; bf16* xb;
  const int* mask; uint32_t* flags;
  const float* w1; const float* w2; const float* wx[4];
  bf16* w1t; bf16* w2t; bf16* wxt[4];
};
__global__ void k_prep(PrepArgs p) {
  __shared__ float tile[64][65];
  const int t = blockIdx.x;
  if (t < 4096) {
    int i = (t * 256 + threadIdx.x) * 8;
    const float4* q = (const float4*)(p.x + i);
    float4 a = q[0], b = q[1];
    bf16x8 v;
    v[0] = (bf16)a.x; v[1] = (bf16)a.y; v[2] = (bf16)a.z; v[3] = (bf16)a.w;
    v[4] = (bf16)b.x; v[5] = (bf16)b.y; v[6] = (bf16)b.z; v[7] = (bf16)b.w;
    *(bf16x8*)(p.xb + i) = v;
    return;
  }
  if (t == 4096) {
    __shared__ uint32_t sb[4];
    int tid = threadIdx.x;
    if (tid < 4) sb[tid] = 0;
    __syncthreads();
    if (tid < 128) {
      int b = tid >> 5, tt = tid & 31;
      const int4* q = (const int4*)(p.mask + b * SEQ + tt * 64);
      int all = 1;
#pragma unroll
      for (int i = 0; i < 16; ++i) {
        int4 v = q[i];
        all &= v.x & v.y & v.z & v.w;
      }
      if (all) atomicOr(&sb[b], 1u << tt);
    }
    __syncthreads();
    if (tid < 4) p.flags[tid] = sb[tid];
    return;
  }
  // transpose tiles (64x64), float4 loads + u16x4 packed stores
  int u = t - 4097;
  const float* W;
  bf16* Wt;
  int K, N, k0, n0;
  if (u < 1024) {
    W = p.w1; Wt = p.w1t; K = 1024; N = 4096;
    k0 = (u & 15) * 64; n0 = (u >> 4) * 64;
  } else if (u < 2048) {
    int v = u - 1024;
    W = p.w2; Wt = p.w2t; K = 4096; N = 1024;
    k0 = (v & 63) * 64; n0 = (v >> 6) * 64;
  } else {
    int v = u - 2048;
    int which = v >> 8, vv = v & 255;
    W = p.wx[which]; Wt = p.wxt[which]; K = 1024; N = 1024;
    k0 = (vv & 15) * 64; n0 = (vv >> 4) * 64;
  }
  const int c4 = threadIdx.x & 15, r0 = threadIdx.x >> 4;  // 16 f4-cols, 16 rows
#pragma unroll
  for (int i = 0; i < 4; ++i) {
    int r = r0 + i * 16;
    float4 v = *(const float4*)&W[(size_t)(k0 + r) * N + n0 + c4 * 4];
    tile[r][c4 * 4 + 0] = v.x;
    tile[r][c4 * 4 + 1] = v.y;
    tile[r][c4 * 4 + 2] = v.z;
    tile[r][c4 * 4 + 3] = v.w;
  }
  __syncthreads();
  const int ch = threadIdx.x & 15;   // k-chunk of 4 (16 lanes = 128B contiguous)
#pragma unroll
  for (int i = 0; i < 4; ++i) {
    int rr = (threadIdx.x >> 4) + i * 16;  // output row (n-dim)
    u16x4 pk = {bfbits(tile[ch * 4 + 0][rr]), bfbits(tile[ch * 4 + 1][rr]),
                bfbits(tile[ch * 4 + 2][rr]), bfbits(tile[ch * 4 + 3][rr])};
    *(u16x4*)&Wt[(size_t)(n0 + rr) * K + k0 + ch * 4] = pk;
  }
}

// ---------------- GEMM 8-phase: C[M,N] = A[M,K] @ Bt[N,K]^T + bias -------
// BM=256, BN=NREP*64; 8 waves (2M x 4N), per-wave 128 x NREP*16.
// REMAP: XCD-2D-tiled block mapping (each XCD owns an 8 x gridDim.y/2
// sub-grid) to cut per-XCD HBM weight re-fetch. Requires gridDim.x==32,
// gridDim.y even. Bijective.
enum { EP_RELU = 0, EP_O16 = 1, EP_QKV = 2 };

template <int EPI, int NREP, bool REMAP>
__global__ __launch_bounds__(512, 2) void k_gemm8(
    const bf16* __restrict__ A, const bf16* __restrict__ Bt,
    const float* __restrict__ bias, const float* __restrict__ bias2,
    const float* __restrict__ bias3,
    void* __restrict__ Cout, void* __restrict__ C2, void* __restrict__ C3,
    int N, int K) {
  extern __shared__ char smem[];
  constexpr int BN = NREP * 64;
  constexpr int HB = NREP / 2;  // B half-tiles per K-tile (2 or 1)
  const int tid = threadIdx.x;
  const int lane = tid & 63;
  const int wid = tid >> 6;
  const int wm = wid >> 2, wn = wid & 3;
  const int l15 = lane & 15, l4 = lane >> 4;
  int bx, by;
  if constexpr (REMAP) {
    const int L = blockIdx.y * 32 + blockIdx.x;
    const int xcd = L & 7, idx = L >> 3;
    bx = (xcd & 3) * 8 + (idx & 7);
    by = (xcd >> 2) * (gridDim.y >> 1) + (idx >> 3);
  } else {
    bx = blockIdx.x;
    by = blockIdx.y;
  }
  const int NI = K >> 7;  // iters of 2 K-tiles (K % 128 == 0)

  const int c0 = tid, c1 = tid + 512;
  const bf16* baseA0 = A + (size_t)(bx * 256 + (c0 >> 3)) * K + ((c0 & 7) ^ ((c0 >> 3) & 7)) * 8;
  const bf16* baseA1 = A + (size_t)(bx * 256 + (c1 >> 3)) * K + ((c1 & 7) ^ ((c1 >> 3) & 7)) * 8;
  const bf16* baseB0 = Bt + (size_t)(by * BN + (c0 >> 3)) * K + ((c0 & 7) ^ ((c0 >> 3) & 7)) * 8;
  const bf16* baseB1 = Bt + (size_t)(by * BN + (c1 >> 3)) * K + ((c1 & 7) ^ ((c1 >> 3) & 7)) * 8;
  const size_t rowK128 = (size_t)128 * K;

  auto stA = [&](int h, int t, int buf) {
    gload_lds16(baseA0 + h * rowK128 + t * 64, smem + buf * 32768 + h * 16384 + c0 * 16);
    gload_lds16(baseA1 + h * rowK128 + t * 64, smem + buf * 32768 + h * 16384 + c1 * 16);
  };
  auto stB = [&](int h, int t, int buf) {
    gload_lds16(baseB0 + h * rowK128 + t * 64,
                smem + 65536 + buf * (HB * 16384) + h * 16384 + c0 * 16);
    gload_lds16(baseB1 + h * rowK128 + t * 64,
                smem + 65536 + buf * (HB * 16384) + h * 16384 + c1 * 16);
  };

  const int ch0 = (l4 ^ (l15 & 7)) * 16;
  const int ch1 = ((4 + l4) ^ (l15 & 7)) * 16;
  const int aoff = l15 * 128;
  int boffh[NREP];
#pragma unroll
  for (int n = 0; n < NREP; ++n) {
    int rB = wn * (NREP * 16) + n * 16 + l15;
    boffh[n] = (rB >> 7) * 16384 + (rB & 127) * 128;
  }

  f32x4 acc[8][NREP] = {};
  bf16x8 breg[NREP][2];

  // prologue: tile0 -> buf0, tile1 -> buf1
  stA(0, 0, 0); stA(1, 0, 0); stB(0, 0, 0);
  if constexpr (HB == 2) stB(1, 0, 0);
  stA(0, 1, 1); stA(1, 1, 1); stB(0, 1, 1);
  if constexpr (HB == 2) stB(1, 1, 1);

  for (int i = 0; i < NI; ++i) {
    const int t1 = 2 * i + 1, t2 = 2 * i + 2;
    const bool notfirst = (i > 0), notlast = (i + 1 < NI);
#pragma unroll
    for (int p = 0; p < 8; ++p) {
      const int q = p & 3;
      const char* Ab = smem + (p >> 2) * 32768 + wm * 16384;
      const char* Bb = smem + 65536 + (p >> 2) * (HB * 16384);
      if (p == 0) {
        if (notfirst) {
          stA(0, t1, 1);
          VMCNT(2);
        } else {
          if constexpr (HB == 2) VMCNT(8); else VMCNT(6);
        }
        __builtin_amdgcn_s_barrier();
      } else if (p == 4) {
        if (notlast) {
          stA(0, t2, 0);
          VMCNT(2);
        } else {
          VMCNT(0);
        }
        __builtin_amdgcn_s_barrier();
      }
      if (q == 0) {
#pragma unroll
        for (int n = 0; n < NREP; ++n) {
          breg[n][0] = *(const bf16x8*)(Bb + boffh[n] + ch0);
          breg[n][1] = *(const bf16x8*)(Bb + boffh[n] + ch1);
        }
      }
      bf16x8 a0k0 = *(const bf16x8*)(Ab + (2 * q + 0) * 2048 + aoff + ch0);
      bf16x8 a0k1 = *(const bf16x8*)(Ab + (2 * q + 0) * 2048 + aoff + ch1);
      bf16x8 a1k0 = *(const bf16x8*)(Ab + (2 * q + 1) * 2048 + aoff + ch0);
      bf16x8 a1k1 = *(const bf16x8*)(Ab + (2 * q + 1) * 2048 + aoff + ch1);
      if (p == 1) { if (notfirst) stA(1, t1, 1); }
      else if (p == 2) { if (notfirst) stB(0, t1, 1); }
      else if (p == 3) { if constexpr (HB == 2) { if (notfirst) stB(1, t1, 1); } }
      else if (p == 5) { if (notlast) stA(1, t2, 0); }
      else if (p == 6) { if (notlast) stB(0, t2, 0); }
      else if (p == 7) { if constexpr (HB == 2) { if (notlast) stB(1, t2, 0); } }
      if (p != 0 && p != 4) __builtin_amdgcn_s_barrier();
      LGKM0();
      __builtin_amdgcn_s_setprio(1);
#pragma unroll
      for (int n = 0; n < NREP; ++n) {
        acc[2 * q + 0][n] = __builtin_amdgcn_mfma_f32_16x16x32_bf16(a0k0, breg[n][0], acc[2 * q + 0][n], 0, 0, 0);
        acc[2 * q + 0][n] = __builtin_amdgcn_mfma_f32_16x16x32_bf16(a0k1, breg[n][1], acc[2 * q + 0][n], 0, 0, 0);
        acc[2 * q + 1][n] = __builtin_amdgcn_mfma_f32_16x16x32_bf16(a1k0, breg[n][0], acc[2 * q + 1][n], 0, 0, 0);
        acc[2 * q + 1][n] = __builtin_amdgcn_mfma_f32_16x16x32_bf16(a1k1, breg[n][1], acc[2 * q + 1][n], 0, 0, 0);
      }
      __builtin_amdgcn_s_setprio(0);
      __builtin_amdgcn_s_barrier();
    }
  }

  // ---- epilogue ----
  constexpr int BPM = 1024 / BN;  // blocks per matrix (QKV decode)
  float bia[NREP];
#pragma unroll
  for (int n = 0; n < NREP; ++n) {
    int colL = wn * (NREP * 16) + n * 16 + l15;
    if constexpr (EPI == EP_QKV) {
      const int g = by / BPM;
      const float* bp = (g == 0) ? bias : (g == 1 ? bias2 : bias3);
      bia[n] = bp[(by % BPM) * BN + colL];
    } else {
      bia[n] = bias[by * BN + colL];
    }
  }
#pragma unroll
  for (int mf = 0; mf < 8; ++mf) {
    int row0 = bx * 256 + wm * 128 + mf * 16 + l4 * 4;
#pragma unroll
    for (int n = 0; n < NREP; ++n) {
      int colL = wn * (NREP * 16) + n * 16 + l15;
      if constexpr (EPI == EP_QKV) {
        const int g = by / BPM;
        int cc = (by % BPM) * BN + colL;
        if (g == 2) {
          int bidx = row0 >> 11, s0 = row0 & 2047;
          u16x4 pk;
#pragma unroll
          for (int r = 0; r < 4; ++r) pk[r] = bfbits(acc[mf][n][r] + bia[n]);
          *(u16x4*)((bf16*)C3 + (((size_t)bidx * HEADS + (cc >> 6)) * D_KH + (cc & 63)) * SEQ + s0) = pk;
        } else if (g == 0) {
          // Q pre-scaled by QSCALE (softmax scale folded in)
          bf16* dst = (bf16*)Cout;
#pragma unroll
          for (int r = 0; r < 4; ++r)
            dst[(size_t)(row0 + r) * 1024 + cc] = (bf16)((acc[mf][n][r] + bia[n]) * QSCALE);
        } else {
          bf16* dst = (bf16*)C2;
#pragma unroll
          for (int r = 0; r < 4; ++r)
            dst[(size_t)(row0 + r) * 1024 + cc] = (bf16)(acc[mf][n][r] + bia[n]);
        }
      } else {
        int col = by * BN + colL;
#pragma unroll
        for (int r = 0; r < 4; ++r) {
          float v = acc[mf][n][r] + bia[n];
          if constexpr (EPI == EP_RELU) v = fmaxf(v, 0.f);
          ((bf16*)Cout)[(size_t)(row0 + r) * N + col] = (bf16)v;
        }
      }
    }
  }
}

// ---------------- flash attention v8 (R10 proven version) ----------------
// 1D grid 1024, XCD-grouped. 4 waves x 32 q-rows. Q pre-scaled; raw
// v_exp_f32. P exchange via permlane swaps; row sums via ones-B MFMA;
// staging pointers hoisted. 16x16 MFMA (32x32 regressed: 4-way LDS bank
// conflicts from 32-row ds_reads are unfixable with gload_lds staging).
__global__ __launch_bounds__(256, 4) void k_attn(
    const bf16* __restrict__ Q, const bf16* __restrict__ Kb,
    const bf16* __restrict__ Vt, const int* __restrict__ mask,
    const uint32_t* __restrict__ Mf, bf16* __restrict__ O) {
  __shared__ bf16 Ks[2][64 * 64];
  __shared__ bf16 Vs[2][64 * 64];
  const int tid = threadIdx.x;
  const int lane = tid & 63;
  const int l15 = lane & 15, l4 = lane >> 4;
  // decode XCD-grouped block id: L = xcd + 8*(qx + 16*yhi), bh = 8*yhi + xcd
  const int L = blockIdx.x;
  const int xcd = L & 7, rest = L >> 3;
  const int qx = rest & 15, yhi = rest >> 4;
  const int bh = yhi * 8 + xcd;
  const int b = bh >> 4, h = bh & 15;
  const size_t qrow0 = (size_t)b * SEQ + qx * 128 + (tid >> 6) * 32;
  const bf16* Kbase = Kb + (size_t)b * SEQ * D_MODEL + h * 64;
  const bf16* Vbase = Vt + (size_t)bh * D_KH * SEQ;
  const int* mbase = mask + b * SEQ;
  const uint32_t mflags = Mf[b];

  bf16x8 qf[2][2];
#pragma unroll
  for (int m = 0; m < 2; ++m)
#pragma unroll
    for (int ks = 0; ks < 2; ++ks)
      qf[m][ks] = *(const bf16x8*)&Q[(qrow0 + m * 16 + l15) * D_MODEL + h * 64 + ks * 32 + l4 * 8];

  f32x4 o[2][4] = {};
  f32x4 rs[2] = {};  // per-lane row sums (rows q = m*16 + l4*4 + r)
  bf16x8 ones;
#pragma unroll
  for (int i = 0; i < 8; ++i) ones[i] = (bf16)1.0f;

  // loop-invariant swizzled LDS read offsets (shared by K and V reads)
  const int koff0 = l15 * 64 + ((l4 * 8) ^ ((l15 & 7) << 3));
  const int koff1 = l15 * 64 + ((32 + l4 * 8) ^ ((l15 & 7) << 3));

  // hoisted staging pointers (advance by constants per tile)
  const int r0_ = tid >> 3, c0_ = (tid & 7) ^ (r0_ & 7);
  const int o1_ = tid + 256;
  const int r1_ = o1_ >> 3, c1_ = (o1_ & 7) ^ (r1_ & 7);
  const bf16* gK0 = Kbase + (size_t)r0_ * D_MODEL + c0_ * 8;
  const bf16* gK1 = Kbase + (size_t)r1_ * D_MODEL + c1_ * 8;
  const bf16* gV0 = Vbase + (size_t)r0_ * SEQ + c0_ * 8;
  const bf16* gV1 = Vbase + (size_t)r1_ * SEQ + c1_ * 8;
  char* ldsK = (char*)&Ks[0][0] + tid * 16;
  char* ldsV = (char*)&Vs[0][0] + tid * 16;

  auto stage = [&](int buf) {
    gload_lds16(gK0, ldsK + buf * 8192);
    gload_lds16(gK1, ldsK + buf * 8192 + 4096);
    gload_lds16(gV0, ldsV + buf * 8192);
    gload_lds16(gV1, ldsV + buf * 8192 + 4096);
    gK0 += 64 * D_MODEL; gK1 += 64 * D_MODEL;
    gV0 += 64; gV1 += 64;
  };

  stage(0);
  __syncthreads();

  for (int kv0 = 0; kv0 < SEQ; kv0 += 64) {
    const int cur = (kv0 >> 6) & 1;
    if (kv0 + 64 < SEQ) stage(cur ^ 1);
    const bf16* Kc = &Ks[cur][0];
    const bf16* Vc = &Vs[cur][0];

    // S^T = K @ Q^T : sf[m][n][r] = S[kv = n*16+l4*4+r][q = m*16+l15]
    f32x4 sf[2][4] = {};
    __builtin_amdgcn_s_setprio(1);
#pragma unroll
    for (int ks = 0; ks < 2; ++ks)
#pragma unroll
      for (int n = 0; n < 4; ++n) {
        bf16x8 kf = *(const bf16x8*)&Kc[(ks ? koff1 : koff0) + n * 1024];
#pragma unroll
        for (int m = 0; m < 2; ++m)
          sf[m][n] = __builtin_amdgcn_mfma_f32_16x16x32_bf16(kf, qf[m][ks], sf[m][n], 0, 0, 0);
      }
    __builtin_amdgcn_s_setprio(0);

    // mask: per-tile all-ones flag (fast path loads nothing per-lane)
    if (__builtin_expect(!((mflags >> (kv0 >> 6)) & 1), 0)) {
#pragma unroll
      for (int n = 0; n < 4; ++n) {
        int4 mk = *(const int4*)&mbase[kv0 + n * 16 + l4 * 4];
#pragma unroll
        for (int r = 0; r < 4; ++r)
          if (((const int*)&mk)[r] == 0) {
            sf[0][n][r] = -1e30f;
            sf[1][n][r] = -1e30f;
          }
      }
    }

    // fixed-max softmax: raw v_exp_f32 (Q pre-scaled) + pack to bf16 pairs
    uint32_t pk[2][4][2];
#pragma unroll
    for (int m = 0; m < 2; ++m) {
#pragma unroll
      for (int n = 0; n < 4; ++n) {
#pragma unroll
        for (int r = 0; r < 4; ++r) sf[m][n][r] = exp2_raw(sf[m][n][r]);
        asm("v_cvt_pk_bf16_f32 %0, %1, %2"
            : "=v"(pk[m][n][0]) : "v"(sf[m][n][0]), "v"(sf[m][n][1]));
        asm("v_cvt_pk_bf16_f32 %0, %1, %2"
            : "=v"(pk[m][n][1]) : "v"(sf[m][n][2]), "v"(sf[m][n][3]));
      }
    }

    // in-register exchange via permlane swaps (derivation in R5/R6 notes)
    bf16x8 pa[2][2];
#pragma unroll
    for (int m = 0; m < 2; ++m)
#pragma unroll
      for (int ks = 0; ks < 2; ++ks) {
        u32x4 w;
#pragma unroll
        for (int hh = 0; hh < 2; ++hh) {
          uint32_t a = pk[m][ks * 2 + 0][hh];
          uint32_t bsw = pk[m][ks * 2 + 1][hh];
          asm("v_permlane32_swap_b32 %0, %1" : "+v"(a), "+v"(bsw));
          asm("v_permlane16_swap_b32 %0, %1" : "+v"(a), "+v"(bsw));
          w[hh] = a;
          w[2 + hh] = bsw;
        }
        pa[ks][m] = __builtin_bit_cast(bf16x8, w);
      }

    // PV + row-sum MFMA (B = ones): rs row layout matches o rows exactly
#pragma unroll
    for (int ks = 0; ks < 2; ++ks) {
      __builtin_amdgcn_s_setprio(1);
#pragma unroll
      for (int n = 0; n < 4; ++n) {
        bf16x8 vf = *(const bf16x8*)&Vc[(ks ? koff1 : koff0) + n * 1024];
#pragma unroll
        for (int m = 0; m < 2; ++m)
          o[m][n] = __builtin_amdgcn_mfma_f32_16x16x32_bf16(pa[ks][m], vf, o[m][n], 0, 0, 0);
      }
#pragma unroll
      for (int m = 0; m < 2; ++m)
        rs[m] = __builtin_amdgcn_mfma_f32_16x16x32_bf16(pa[ks][m], ones, rs[m], 0, 0, 0);
      __builtin_amdgcn_s_setprio(0);
    }
    __syncthreads();
  }

  // epilogue: normalize (row sums already per-lane in rs)
#pragma unroll
  for (int m = 0; m < 2; ++m) {
    float inv[4];
#pragma unroll
    for (int r = 0; r < 4; ++r) inv[r] = 1.0f / rs[m][r];
#pragma unroll
    for (int n = 0; n < 4; ++n)
#pragma unroll
      for (int r = 0; r < 4; ++r)
        O[(qrow0 + m * 16 + l4 * 4 + r) * D_MODEL + h * 64 + n * 16 + l15] =
            (bf16)(o[m][n][r] * inv[r]);
  }
}

// ------- fused residual add + LayerNorm, wave-per-row (no barrier/LDS) ---
// 4 rows / 256-thread block; each lane owns 16 consecutive elements.
template <bool F32OUT>
__global__ __launch_bounds__(256) void k_add_ln(
    const bf16* __restrict__ a, const bf16* __restrict__ b,
    const float* __restrict__ g, const float* __restrict__ be,
    void* __restrict__ y) {
  const int lane = threadIdx.x & 63;
  const size_t row = (size_t)blockIdx.x * 4 + (threadIdx.x >> 6);
  const size_t base = row * D_MODEL + lane * 16;
  uint4 a0 = *(const uint4*)(a + base);
  uint4 a1 = *(const uint4*)(a + base + 8);
  uint4 b0 = *(const uint4*)(b + base);
  uint4 b1 = *(const uint4*)(b + base + 8);
  float v[16];
  const uint32_t* pa0 = (const uint32_t*)&a0;
  const uint32_t* pb0 = (const uint32_t*)&b0;
  const uint32_t* pa1 = (const uint32_t*)&a1;
  const uint32_t* pb1 = (const uint32_t*)&b1;
#pragma unroll
  for (int i = 0; i < 4; ++i) {
    v[2 * i + 0] = bf2f_lo(pa0[i]) + bf2f_lo(pb0[i]);
    v[2 * i + 1] = bf2f_hi(pa0[i]) + bf2f_hi(pb0[i]);
    v[8 + 2 * i + 0] = bf2f_lo(pa1[i]) + bf2f_lo(pb1[i]);
    v[8 + 2 * i + 1] = bf2f_hi(pa1[i]) + bf2f_hi(pb1[i]);
  }
  float s = 0.f, s2 = 0.f;
#pragma unroll
  for (int i = 0; i < 16; ++i) {
    s += v[i];
    s2 = fmaf(v[i], v[i], s2);
  }
#pragma unroll
  for (int off = 1; off < 64; off <<= 1) {
    s  += __shfl_xor(s, off);
    s2 += __shfl_xor(s2, off);
  }
  float mu  = s * (1.f / D_MODEL);
  float var = s2 * (1.f / D_MODEL) - mu * mu;
  float rstd = rsqrtf(var + 1e-5f);
  const float4* gp = (const float4*)(g + lane * 16);
  const float4* bp = (const float4*)(be + lane * 16);
#pragma unroll
  for (int i = 0; i < 4; ++i) {
    float4 gg = gp[i], bb = bp[i];
    float y0 = (v[4 * i + 0] - mu) * rstd * gg.x + bb.x;
    float y1 = (v[4 * i + 1] - mu) * rstd * gg.y + bb.y;
    float y2 = (v[4 * i + 2] - mu) * rstd * gg.z + bb.z;
    float y3 = (v[4 * i + 3] - mu) * rstd * gg.w + bb.w;
    if constexpr (F32OUT) {
      *(float4*)((float*)y + base + 4 * i) = make_float4(y0, y1, y2, y3);
    } else {
      u16x4 pk = {bfbits(y0), bfbits(y1), bfbits(y2), bfbits(y3)};
      *(u16x4*)((bf16*)y + base + 4 * i) = pk;
    }
  }
}

// ---------------- orchestration ----------------
extern "C" void kernel_launch(void* const* d_in, const int* in_sizes, int n_in,
                              void* d_out, int out_size, void* d_ws, size_t ws_size,
                              hipStream_t stream) {
  const float* x   = (const float*)d_in[0];
  const int*  mask = (const int*)d_in[1];
  const float* Wq  = (const float*)d_in[2];
  const float* bq  = (const float*)d_in[3];
  const float* Wk  = (const float*)d_in[4];
  const float* bk_ = (const float*)d_in[5];
  const float* Wv  = (const float*)d_in[6];
  const float* bv  = (const float*)d_in[7];
  const float* Wo  = (const float*)d_in[8];
  const float* bo  = (const float*)d_in[9];
  const float* W1  = (const float*)d_in[10];
  const float* b1  = (const float*)d_in[11];
  const float* W2  = (const float*)d_in[12];
  const float* b2  = (const float*)d_in[13];
  const float* g1  = (const float*)d_in[14];
  const float* be1 = (const float*)d_in[15];
  const float* g2  = (const float*)d_in[16];
  const float* be2 = (const float*)d_in[17];

  char* ws = (char*)d_ws;
  const size_t MB = 1ull << 20;
  bf16*  xb    = (bf16*)(ws + 0);          // 16MB (live until LN1)
  bf16*  Qb    = (bf16*)(ws + 16 * MB);    // 16MB (pre-scaled Q)
  bf16*  Kbuf  = (bf16*)(ws + 32 * MB);    // 16MB
  bf16*  Vt    = (bf16*)(ws + 48 * MB);    // 16MB [B,H,64,S]
  bf16*  Hb    = (bf16*)(ws + 0);          // 64MB FFN hidden (xb..Vt dead)
  bf16*  aproj = (bf16*)(ws + 64 * MB);    // 16MB Wo output
  bf16*  f2o   = (bf16*)(ws + 80 * MB);    // 16MB FFN2 output
  bf16*  Ob    = (bf16*)(ws + 96 * MB);    // 16MB attention output
  uint32_t* mfl = (uint32_t*)(ws + 112 * MB);  // 16B
  bf16*  x1b   = (bf16*)(ws + 128 * MB);   // 16MB LN1 output
  bf16*  Wqkvt = (bf16*)(ws + 144 * MB);   // 6MB [3072,1024]
  bf16*  Wot   = (bf16*)(ws + 150 * MB);   // 2MB
  bf16*  W1t   = (bf16*)(ws + 152 * MB);   // 8MB [4096,1024]
  bf16*  W2t   = (bf16*)(ws + 160 * MB);   // 8MB [1024,4096]

  const int SM4 = 131072, SM2 = 98304;
  hipFuncSetAttribute(reinterpret_cast<const void*>(&k_gemm8<EP_QKV, 2, true>),
                      hipFuncAttributeMaxDynamicSharedMemorySize, SM2);
  hipFuncSetAttribute(reinterpret_cast<const void*>(&k_gemm8<EP_RELU, 4, true>),
                      hipFuncAttributeMaxDynamicSharedMemorySize, SM4);
  hipFuncSetAttribute(reinterpret_cast<const void*>(&k_gemm8<EP_O16, 2, true>),
                      hipFuncAttributeMaxDynamicSharedMemorySize, SM2);
  hipFuncSetAttribute(reinterpret_cast<const void*>(&k_gemm8<EP_O16, 2, false>),
                      hipFuncAttributeMaxDynamicSharedMemorySize, SM2);

  PrepArgs pp;
  pp.x = x; pp.xb = xb; pp.mask = mask; pp.flags = mfl;
  pp.w1 = W1; pp.w1t = W1t;
  pp.w2 = W2; pp.w2t = W2t;
  pp.wx[0] = Wq; pp.wxt[0] = Wqkvt;
  pp.wx[1] = Wk; pp.wxt[1] = Wqkvt + 1024 * 1024;
  pp.wx[2] = Wv; pp.wxt[2] = Wqkvt + 2 * 1024 * 1024;
  pp.wx[3] = Wo; pp.wxt[3] = Wot;
  k_prep<<<7169, 256, 0, stream>>>(pp);

  // fused QKV: N=3072, BN=128, grid 32x24 = 768 blocks (3 exact rounds)
  k_gemm8<EP_QKV, 2, true><<<dim3(32, 24), 512, SM2, stream>>>(
      xb, Wqkvt, bq, bk_, bv, Qb, Kbuf, Vt, 3072, 1024);

  k_attn<<<1024, 256, 0, stream>>>(Qb, Kbuf, Vt, mask, mfl, Ob);

  k_gemm8<EP_O16, 2, false><<<dim3(32, 8), 512, SM2, stream>>>(
      Ob, Wot, bo, nullptr, nullptr, aproj, nullptr, nullptr, 1024, 1024);
  k_add_ln<false><<<MROWS / 4, 256, 0, stream>>>(xb, aproj, g1, be1, x1b);

  k_gemm8<EP_RELU, 4, true><<<dim3(32, 16), 512, SM4, stream>>>(
      x1b, W1t, b1, nullptr, nullptr, Hb, nullptr, nullptr, 4096, 1024);
  k_gemm8<EP_O16, 2, true><<<dim3(32, 8), 512, SM2, stream>>>(
      Hb, W2t, b2, nullptr, nullptr, f2o, nullptr, nullptr, 1024, 4096);
  k_add_ln<true><<<MROWS / 4, 256, 0, stream>>>(x1b, f2o, g2, be2, (float*)d_out);
}

// Round 14
// 328.296 us; speedup vs baseline: 1.0124x; 1.0124x over previous
//
#include <hip/hip_runtime.h>
#include <hip/hip_bf16.h>
#include <cstdint>
#include <cstddef>

typedef __bf16 bf16;
typedef __bf16 bf16x8 __attribute__((ext_vector_type(8)));
typedef float  f32x4  __attribute__((ext_vector_type(4)));
typedef unsigned short u16x4 __attribute__((ext_vector_type(4)));
typedef uint32_t u32x4 __attribute__((ext_vector_type(4)));

static constexpr int D_MODEL = 1024;
static constexpr int HEADS   = 16;
static constexpr int D_KH    = 64;
static constexpr int D_FF    = 4096;
static constexpr int BATCH   = 4;
static constexpr int SEQ     = 2048;
static constexpr int MROWS   = BATCH * SEQ;  // 8192
static constexpr float QSCALE = 0.18033688011f;  // (1/sqrt(64)) * log2(e)

#define VMCNT(n) asm volatile("s_waitcnt vmcnt(" #n ")" ::: "memory")
#define LGKM0()                                            \
  do {                                                     \
    asm volatile("s_waitcnt lgkmcnt(0)" ::: "memory");     \
    __builtin_amdgcn_sched_barrier(0);                     \
  } while (0)

__device__ __forceinline__ unsigned short bfbits(float f) {
  return __builtin_bit_cast(unsigned short, (bf16)f);
}
__device__ __forceinline__ float bf2f(unsigned short u) {
  return __builtin_bit_cast(float, (uint32_t)u << 16);
}
__device__ __forceinline__ float bf2f_hi(uint32_t w) {
  return __builtin_bit_cast(float, w & 0xffff0000u);
}
__device__ __forceinline__ float bf2f_lo(uint32_t w) {
  return __builtin_bit_cast(float, w << 16);
}
// raw HW exp2 (inputs bounded; no denormal fixup needed)
__device__ __forceinline__ float exp2_raw(float x) {
  float r;
  asm("v_exp_f32 %0, %1" : "=v"(r) : "v"(x));
  return r;
}

__device__ __forceinline__ void gload_lds16(const void* g, void* l) {
  __builtin_amdgcn_global_load_lds(
      (__attribute__((address_space(1))) uint32_t*)(uintptr_t)g,
      (__attribute__((address_space(3))) uint32_t*)(uintptr_t)l, 16, 0, 0);
}

// -------- one prep kernel: x cast (0..4095), mask flags (4096),
//          all weight transposes (4097..7168), vectorized both sides ----
struct PrepArgs {
  const float* x; bf16* xb;
  const int* mask; uint32_t* flags;
  const float* w1; const float* w2; const float* wx[4];
  bf16* w1t; bf16* w2t; bf16* wxt[4];
};
__global__ void k_prep(PrepArgs p) {
  __shared__ float tile[64][65];
  const int t = blockIdx.x;
  if (t < 4096) {
    int i = (t * 256 + threadIdx.x) * 8;
    const float4* q = (const float4*)(p.x + i);
    float4 a = q[0], b = q[1];
    bf16x8 v;
    v[0] = (bf16)a.x; v[1] = (bf16)a.y; v[2] = (bf16)a.z; v[3] = (bf16)a.w;
    v[4] = (bf16)b.x; v[5] = (bf16)b.y; v[6] = (bf16)b.z; v[7] = (bf16)b.w;
    *(bf16x8*)(p.xb + i) = v;
    return;
  }
  if (t == 4096) {
    __shared__ uint32_t sb[4];
    int tid = threadIdx.x;
    if (tid < 4) sb[tid] = 0;
    __syncthreads();
    if (tid < 128) {
      int b = tid >> 5, tt = tid & 31;
      const int4* q = (const int4*)(p.mask + b * SEQ + tt * 64);
      int all = 1;
#pragma unroll
      for (int i = 0; i < 16; ++i) {
        int4 v = q[i];
        all &= v.x & v.y & v.z & v.w;
      }
      if (all) atomicOr(&sb[b], 1u << tt);
    }
    __syncthreads();
    if (tid < 4) p.flags[tid] = sb[tid];
    return;
  }
  // transpose tiles (64x64), float4 loads + u16x4 packed stores
  int u = t - 4097;
  const float* W;
  bf16* Wt;
  int K, N, k0, n0;
  if (u < 1024) {
    W = p.w1; Wt = p.w1t; K = 1024; N = 4096;
    k0 = (u & 15) * 64; n0 = (u >> 4) * 64;
  } else if (u < 2048) {
    int v = u - 1024;
    W = p.w2; Wt = p.w2t; K = 4096; N = 1024;
    k0 = (v & 63) * 64; n0 = (v >> 6) * 64;
  } else {
    int v = u - 2048;
    int which = v >> 8, vv = v & 255;
    W = p.wx[which]; Wt = p.wxt[which]; K = 1024; N = 1024;
    k0 = (vv & 15) * 64; n0 = (vv >> 4) * 64;
  }
  const int c4 = threadIdx.x & 15, r0 = threadIdx.x >> 4;  // 16 f4-cols, 16 rows
#pragma unroll
  for (int i = 0; i < 4; ++i) {
    int r = r0 + i * 16;
    float4 v = *(const float4*)&W[(size_t)(k0 + r) * N + n0 + c4 * 4];
    tile[r][c4 * 4 + 0] = v.x;
    tile[r][c4 * 4 + 1] = v.y;
    tile[r][c4 * 4 + 2] = v.z;
    tile[r][c4 * 4 + 3] = v.w;
  }
  __syncthreads();
  const int ch = threadIdx.x & 15;   // k-chunk of 4 (16 lanes = 128B contiguous)
#pragma unroll
  for (int i = 0; i < 4; ++i) {
    int rr = (threadIdx.x >> 4) + i * 16;  // output row (n-dim)
    u16x4 pk = {bfbits(tile[ch * 4 + 0][rr]), bfbits(tile[ch * 4 + 1][rr]),
                bfbits(tile[ch * 4 + 2][rr]), bfbits(tile[ch * 4 + 3][rr])};
    *(u16x4*)&Wt[(size_t)(n0 + rr) * K + k0 + ch * 4] = pk;
  }
}

// ---------------- GEMM 8-phase: C[M,N] = A[M,K] @ Bt[N,K]^T + bias -------
// BM=256, BN=NREP*64; 8 waves (2M x 4N), per-wave 128 x NREP*16.
// (R13's XCD remap reverted: weights are L3-resident, remap only hurt.)
enum { EP_RELU = 0, EP_O16 = 1, EP_QKV = 2 };

template <int EPI, int NREP>
__global__ __launch_bounds__(512, 2) void k_gemm8(
    const bf16* __restrict__ A, const bf16* __restrict__ Bt,
    const float* __restrict__ bias, const float* __restrict__ bias2,
    const float* __restrict__ bias3,
    void* __restrict__ Cout, void* __restrict__ C2, void* __restrict__ C3,
    int N, int K) {
  extern __shared__ char smem[];
  constexpr int BN = NREP * 64;
  constexpr int HB = NREP / 2;  // B half-tiles per K-tile (2 or 1)
  const int tid = threadIdx.x;
  const int lane = tid & 63;
  const int wid = tid >> 6;
  const int wm = wid >> 2, wn = wid & 3;
  const int l15 = lane & 15, l4 = lane >> 4;
  const int bx = blockIdx.x, by = blockIdx.y;
  const int NI = K >> 7;  // iters of 2 K-tiles (K % 128 == 0)

  const int c0 = tid, c1 = tid + 512;
  const bf16* baseA0 = A + (size_t)(bx * 256 + (c0 >> 3)) * K + ((c0 & 7) ^ ((c0 >> 3) & 7)) * 8;
  const bf16* baseA1 = A + (size_t)(bx * 256 + (c1 >> 3)) * K + ((c1 & 7) ^ ((c1 >> 3) & 7)) * 8;
  const bf16* baseB0 = Bt + (size_t)(by * BN + (c0 >> 3)) * K + ((c0 & 7) ^ ((c0 >> 3) & 7)) * 8;
  const bf16* baseB1 = Bt + (size_t)(by * BN + (c1 >> 3)) * K + ((c1 & 7) ^ ((c1 >> 3) & 7)) * 8;
  const size_t rowK128 = (size_t)128 * K;

  auto stA = [&](int h, int t, int buf) {
    gload_lds16(baseA0 + h * rowK128 + t * 64, smem + buf * 32768 + h * 16384 + c0 * 16);
    gload_lds16(baseA1 + h * rowK128 + t * 64, smem + buf * 32768 + h * 16384 + c1 * 16);
  };
  auto stB = [&](int h, int t, int buf) {
    gload_lds16(baseB0 + h * rowK128 + t * 64,
                smem + 65536 + buf * (HB * 16384) + h * 16384 + c0 * 16);
    gload_lds16(baseB1 + h * rowK128 + t * 64,
                smem + 65536 + buf * (HB * 16384) + h * 16384 + c1 * 16);
  };

  const int ch0 = (l4 ^ (l15 & 7)) * 16;
  const int ch1 = ((4 + l4) ^ (l15 & 7)) * 16;
  const int aoff = l15 * 128;
  int boffh[NREP];
#pragma unroll
  for (int n = 0; n < NREP; ++n) {
    int rB = wn * (NREP * 16) + n * 16 + l15;
    boffh[n] = (rB >> 7) * 16384 + (rB & 127) * 128;
  }

  f32x4 acc[8][NREP] = {};
  bf16x8 breg[NREP][2];

  // prologue: tile0 -> buf0, tile1 -> buf1
  stA(0, 0, 0); stA(1, 0, 0); stB(0, 0, 0);
  if constexpr (HB == 2) stB(1, 0, 0);
  stA(0, 1, 1); stA(1, 1, 1); stB(0, 1, 1);
  if constexpr (HB == 2) stB(1, 1, 1);

  for (int i = 0; i < NI; ++i) {
    const int t1 = 2 * i + 1, t2 = 2 * i + 2;
    const bool notfirst = (i > 0), notlast = (i + 1 < NI);
#pragma unroll
    for (int p = 0; p < 8; ++p) {
      const int q = p & 3;
      const char* Ab = smem + (p >> 2) * 32768 + wm * 16384;
      const char* Bb = smem + 65536 + (p >> 2) * (HB * 16384);
      if (p == 0) {
        if (notfirst) {
          stA(0, t1, 1);
          VMCNT(2);
        } else {
          if constexpr (HB == 2) VMCNT(8); else VMCNT(6);
        }
        __builtin_amdgcn_s_barrier();
      } else if (p == 4) {
        if (notlast) {
          stA(0, t2, 0);
          VMCNT(2);
        } else {
          VMCNT(0);
        }
        __builtin_amdgcn_s_barrier();
      }
      if (q == 0) {
#pragma unroll
        for (int n = 0; n < NREP; ++n) {
          breg[n][0] = *(const bf16x8*)(Bb + boffh[n] + ch0);
          breg[n][1] = *(const bf16x8*)(Bb + boffh[n] + ch1);
        }
      }
      bf16x8 a0k0 = *(const bf16x8*)(Ab + (2 * q + 0) * 2048 + aoff + ch0);
      bf16x8 a0k1 = *(const bf16x8*)(Ab + (2 * q + 0) * 2048 + aoff + ch1);
      bf16x8 a1k0 = *(const bf16x8*)(Ab + (2 * q + 1) * 2048 + aoff + ch0);
      bf16x8 a1k1 = *(const bf16x8*)(Ab + (2 * q + 1) * 2048 + aoff + ch1);
      if (p == 1) { if (notfirst) stA(1, t1, 1); }
      else if (p == 2) { if (notfirst) stB(0, t1, 1); }
      else if (p == 3) { if constexpr (HB == 2) { if (notfirst) stB(1, t1, 1); } }
      else if (p == 5) { if (notlast) stA(1, t2, 0); }
      else if (p == 6) { if (notlast) stB(0, t2, 0); }
      else if (p == 7) { if constexpr (HB == 2) { if (notlast) stB(1, t2, 0); } }
      if (p != 0 && p != 4) __builtin_amdgcn_s_barrier();
      LGKM0();
      __builtin_amdgcn_s_setprio(1);
#pragma unroll
      for (int n = 0; n < NREP; ++n) {
        acc[2 * q + 0][n] = __builtin_amdgcn_mfma_f32_16x16x32_bf16(a0k0, breg[n][0], acc[2 * q + 0][n], 0, 0, 0);
        acc[2 * q + 0][n] = __builtin_amdgcn_mfma_f32_16x16x32_bf16(a0k1, breg[n][1], acc[2 * q + 0][n], 0, 0, 0);
        acc[2 * q + 1][n] = __builtin_amdgcn_mfma_f32_16x16x32_bf16(a1k0, breg[n][0], acc[2 * q + 1][n], 0, 0, 0);
        acc[2 * q + 1][n] = __builtin_amdgcn_mfma_f32_16x16x32_bf16(a1k1, breg[n][1], acc[2 * q + 1][n], 0, 0, 0);
      }
      __builtin_amdgcn_s_setprio(0);
      __builtin_amdgcn_s_barrier();
    }
  }

  // ---- epilogue ----
  constexpr int BPM = 1024 / BN;  // blocks per matrix (QKV decode)
  float bia[NREP];
#pragma unroll
  for (int n = 0; n < NREP; ++n) {
    int colL = wn * (NREP * 16) + n * 16 + l15;
    if constexpr (EPI == EP_QKV) {
      const int g = by / BPM;
      const float* bp = (g == 0) ? bias : (g == 1 ? bias2 : bias3);
      bia[n] = bp[(by % BPM) * BN + colL];
    } else {
      bia[n] = bias[by * BN + colL];
    }
  }
#pragma unroll
  for (int mf = 0; mf < 8; ++mf) {
    int row0 = bx * 256 + wm * 128 + mf * 16 + l4 * 4;
#pragma unroll
    for (int n = 0; n < NREP; ++n) {
      int colL = wn * (NREP * 16) + n * 16 + l15;
      if constexpr (EPI == EP_QKV) {
        const int g = by / BPM;
        int cc = (by % BPM) * BN + colL;
        if (g == 2) {
          int bidx = row0 >> 11, s0 = row0 & 2047;
          u16x4 pk;
#pragma unroll
          for (int r = 0; r < 4; ++r) pk[r] = bfbits(acc[mf][n][r] + bia[n]);
          *(u16x4*)((bf16*)C3 + (((size_t)bidx * HEADS + (cc >> 6)) * D_KH + (cc & 63)) * SEQ + s0) = pk;
        } else if (g == 0) {
          // Q pre-scaled by QSCALE (softmax scale folded in)
          bf16* dst = (bf16*)Cout;
#pragma unroll
          for (int r = 0; r < 4; ++r)
            dst[(size_t)(row0 + r) * 1024 + cc] = (bf16)((acc[mf][n][r] + bia[n]) * QSCALE);
        } else {
          bf16* dst = (bf16*)C2;
#pragma unroll
          for (int r = 0; r < 4; ++r)
            dst[(size_t)(row0 + r) * 1024 + cc] = (bf16)(acc[mf][n][r] + bia[n]);
        }
      } else {
        int col = by * BN + colL;
#pragma unroll
        for (int r = 0; r < 4; ++r) {
          float v = acc[mf][n][r] + bia[n];
          if constexpr (EPI == EP_RELU) v = fmaxf(v, 0.f);
          ((bf16*)Cout)[(size_t)(row0 + r) * N + col] = (bf16)v;
        }
      }
    }
  }
}

// ---------------- flash attention v10 -----------------
// R12 structure + per-block ROTATED kv iteration order (fixed-max softmax
// is commutative over tiles -> bit-identical result). Co-resident blocks
// sit at different compute phases, letting one block's VALU overlap
// another's MFMA instead of chip-wide lockstep.
__global__ __launch_bounds__(256, 4) void k_attn(
    const bf16* __restrict__ Q, const bf16* __restrict__ Kb,
    const bf16* __restrict__ Vt, const int* __restrict__ mask,
    const uint32_t* __restrict__ Mf, bf16* __restrict__ O) {
  __shared__ bf16 Ks[2][64 * 64];
  __shared__ bf16 Vs[2][64 * 64];
  const int tid = threadIdx.x;
  const int lane = tid & 63;
  const int l15 = lane & 15, l4 = lane >> 4;
  // decode XCD-grouped block id: L = xcd + 8*(qx + 16*yhi), bh = 8*yhi + xcd
  const int L = blockIdx.x;
  const int xcd = L & 7, rest = L >> 3;
  const int qx = rest & 15, yhi = rest >> 4;
  const int bh = yhi * 8 + xcd;
  const int b = bh >> 4, h = bh & 15;
  const int rot = rest & 31;  // per-block kv phase rotation
  const size_t qrow0 = (size_t)b * SEQ + qx * 128 + (tid >> 6) * 32;
  const bf16* Kbase = Kb + (size_t)b * SEQ * D_MODEL + h * 64;
  const bf16* Vbase = Vt + (size_t)bh * D_KH * SEQ;
  const int* mbase = mask + b * SEQ;
  const uint32_t mflags = Mf[b];

  bf16x8 qf[2][2];
#pragma unroll
  for (int m = 0; m < 2; ++m)
#pragma unroll
    for (int ks = 0; ks < 2; ++ks)
      qf[m][ks] = *(const bf16x8*)&Q[(qrow0 + m * 16 + l15) * D_MODEL + h * 64 + ks * 32 + l4 * 8];

  f32x4 o[2][4] = {};
  f32x4 rs[2] = {};  // per-lane row sums (rows q = m*16 + l4*4 + r)
  bf16x8 ones;
#pragma unroll
  for (int i = 0; i < 8; ++i) ones[i] = (bf16)1.0f;

  // loop-invariant swizzled LDS read offsets (shared by K and V reads)
  const int koff0 = l15 * 64 + ((l4 * 8) ^ ((l15 & 7) << 3));
  const int koff1 = l15 * 64 + ((32 + l4 * 8) ^ ((l15 & 7) << 3));

  // per-thread staging offsets (element units)
  const int r0_ = tid >> 3, c0_ = (tid & 7) ^ (r0_ & 7);
  const int o1_ = tid + 256;
  const int r1_ = o1_ >> 3, c1_ = (o1_ & 7) ^ (r1_ & 7);
  const size_t kO0 = (size_t)r0_ * D_MODEL + c0_ * 8;
  const size_t kO1 = (size_t)r1_ * D_MODEL + c1_ * 8;
  const size_t vO0 = (size_t)r0_ * SEQ + c0_ * 8;
  const size_t vO1 = (size_t)r1_ * SEQ + c1_ * 8;
  char* ldsK = (char*)&Ks[0][0] + tid * 16;
  char* ldsV = (char*)&Vs[0][0] + tid * 16;

  auto stage = [&](int buf, int kv0) {
    gload_lds16(Kbase + (size_t)kv0 * D_MODEL + kO0, ldsK + buf * 8192);
    gload_lds16(Kbase + (size_t)kv0 * D_MODEL + kO1, ldsK + buf * 8192 + 4096);
    gload_lds16(Vbase + kv0 + vO0, ldsV + buf * 8192);
    gload_lds16(Vbase + kv0 + vO1, ldsV + buf * 8192 + 4096);
  };

  stage(0, (rot & 31) * 64);
  __syncthreads();

  for (int it = 0; it < 32; ++it) {
    const int kv0 = ((it + rot) & 31) * 64;
    const int cur = it & 1;
    if (it + 1 < 32) stage(cur ^ 1, ((it + 1 + rot) & 31) * 64);
    const bf16* Kc = &Ks[cur][0];
    const bf16* Vc = &Vs[cur][0];

    // S^T = K @ Q^T : sf[m][n][r] = S[kv = n*16+l4*4+r][q = m*16+l15]
    f32x4 sf[2][4] = {};
    __builtin_amdgcn_s_setprio(1);
#pragma unroll
    for (int ks = 0; ks < 2; ++ks)
#pragma unroll
      for (int n = 0; n < 4; ++n) {
        bf16x8 kf = *(const bf16x8*)&Kc[(ks ? koff1 : koff0) + n * 1024];
#pragma unroll
        for (int m = 0; m < 2; ++m)
          sf[m][n] = __builtin_amdgcn_mfma_f32_16x16x32_bf16(kf, qf[m][ks], sf[m][n], 0, 0, 0);
      }
    __builtin_amdgcn_s_setprio(0);

    // mask: per-tile all-ones flag (fast path loads nothing per-lane)
    if (__builtin_expect(!((mflags >> (kv0 >> 6)) & 1), 0)) {
#pragma unroll
      for (int n = 0; n < 4; ++n) {
        int4 mk = *(const int4*)&mbase[kv0 + n * 16 + l4 * 4];
#pragma unroll
        for (int r = 0; r < 4; ++r)
          if (((const int*)&mk)[r] == 0) {
            sf[0][n][r] = -1e30f;
            sf[1][n][r] = -1e30f;
          }
      }
    }

    // fixed-max softmax: raw v_exp_f32 (Q pre-scaled) + pack to bf16 pairs
    uint32_t pk[2][4][2];
#pragma unroll
    for (int m = 0; m < 2; ++m) {
#pragma unroll
      for (int n = 0; n < 4; ++n) {
#pragma unroll
        for (int r = 0; r < 4; ++r) sf[m][n][r] = exp2_raw(sf[m][n][r]);
        asm("v_cvt_pk_bf16_f32 %0, %1, %2"
            : "=v"(pk[m][n][0]) : "v"(sf[m][n][0]), "v"(sf[m][n][1]));
        asm("v_cvt_pk_bf16_f32 %0, %1, %2"
            : "=v"(pk[m][n][1]) : "v"(sf[m][n][2]), "v"(sf[m][n][3]));
      }
    }

    // in-register exchange via permlane swaps (derivation in R5/R6 notes)
    bf16x8 pa[2][2];
#pragma unroll
    for (int m = 0; m < 2; ++m)
#pragma unroll
      for (int ks = 0; ks < 2; ++ks) {
        u32x4 w;
#pragma unroll
        for (int hh = 0; hh < 2; ++hh) {
          uint32_t a = pk[m][ks * 2 + 0][hh];
          uint32_t bsw = pk[m][ks * 2 + 1][hh];
          asm("v_permlane32_swap_b32 %0, %1" : "+v"(a), "+v"(bsw));
          asm("v_permlane16_swap_b32 %0, %1" : "+v"(a), "+v"(bsw));
          w[hh] = a;
          w[2 + hh] = bsw;
        }
        pa[ks][m] = __builtin_bit_cast(bf16x8, w);
      }

    // PV + row-sum MFMA (B = ones): rs row layout matches o rows exactly
#pragma unroll
    for (int ks = 0; ks < 2; ++ks) {
      __builtin_amdgcn_s_setprio(1);
#pragma unroll
      for (int n = 0; n < 4; ++n) {
        bf16x8 vf = *(const bf16x8*)&Vc[(ks ? koff1 : koff0) + n * 1024];
#pragma unroll
        for (int m = 0; m < 2; ++m)
          o[m][n] = __builtin_amdgcn_mfma_f32_16x16x32_bf16(pa[ks][m], vf, o[m][n], 0, 0, 0);
      }
#pragma unroll
      for (int m = 0; m < 2; ++m)
        rs[m] = __builtin_amdgcn_mfma_f32_16x16x32_bf16(pa[ks][m], ones, rs[m], 0, 0, 0);
      __builtin_amdgcn_s_setprio(0);
    }
    __syncthreads();
  }

  // epilogue: normalize (row sums already per-lane in rs)
#pragma unroll
  for (int m = 0; m < 2; ++m) {
    float inv[4];
#pragma unroll
    for (int r = 0; r < 4; ++r) inv[r] = 1.0f / rs[m][r];
#pragma unroll
    for (int n = 0; n < 4; ++n)
#pragma unroll
      for (int r = 0; r < 4; ++r)
        O[(qrow0 + m * 16 + l4 * 4 + r) * D_MODEL + h * 64 + n * 16 + l15] =
            (bf16)(o[m][n][r] * inv[r]);
  }
}

// ------- fused residual add + LayerNorm, wave-per-row (no barrier/LDS) ---
// 4 rows / 256-thread block; each lane owns 16 consecutive elements.
template <bool F32OUT>
__global__ __launch_bounds__(256) void k_add_ln(
    const bf16* __restrict__ a, const bf16* __restrict__ b,
    const float* __restrict__ g, const float* __restrict__ be,
    void* __restrict__ y) {
  const int lane = threadIdx.x & 63;
  const size_t row = (size_t)blockIdx.x * 4 + (threadIdx.x >> 6);
  const size_t base = row * D_MODEL + lane * 16;
  uint4 a0 = *(const uint4*)(a + base);
  uint4 a1 = *(const uint4*)(a + base + 8);
  uint4 b0 = *(const uint4*)(b + base);
  uint4 b1 = *(const uint4*)(b + base + 8);
  float v[16];
  const uint32_t* pa0 = (const uint32_t*)&a0;
  const uint32_t* pb0 = (const uint32_t*)&b0;
  const uint32_t* pa1 = (const uint32_t*)&a1;
  const uint32_t* pb1 = (const uint32_t*)&b1;
#pragma unroll
  for (int i = 0; i < 4; ++i) {
    v[2 * i + 0] = bf2f_lo(pa0[i]) + bf2f_lo(pb0[i]);
    v[2 * i + 1] = bf2f_hi(pa0[i]) + bf2f_hi(pb0[i]);
    v[8 + 2 * i + 0] = bf2f_lo(pa1[i]) + bf2f_lo(pb1[i]);
    v[8 + 2 * i + 1] = bf2f_hi(pa1[i]) + bf2f_hi(pb1[i]);
  }
  float s = 0.f, s2 = 0.f;
#pragma unroll
  for (int i = 0; i < 16; ++i) {
    s += v[i];
    s2 = fmaf(v[i], v[i], s2);
  }
#pragma unroll
  for (int off = 1; off < 64; off <<= 1) {
    s  += __shfl_xor(s, off);
    s2 += __shfl_xor(s2, off);
  }
  float mu  = s * (1.f / D_MODEL);
  float var = s2 * (1.f / D_MODEL) - mu * mu;
  float rstd = rsqrtf(var + 1e-5f);
  const float4* gp = (const float4*)(g + lane * 16);
  const float4* bp = (const float4*)(be + lane * 16);
#pragma unroll
  for (int i = 0; i < 4; ++i) {
    float4 gg = gp[i], bb = bp[i];
    float y0 = (v[4 * i + 0] - mu) * rstd * gg.x + bb.x;
    float y1 = (v[4 * i + 1] - mu) * rstd * gg.y + bb.y;
    float y2 = (v[4 * i + 2] - mu) * rstd * gg.z + bb.z;
    float y3 = (v[4 * i + 3] - mu) * rstd * gg.w + bb.w;
    if constexpr (F32OUT) {
      *(float4*)((float*)y + base + 4 * i) = make_float4(y0, y1, y2, y3);
    } else {
      u16x4 pk = {bfbits(y0), bfbits(y1), bfbits(y2), bfbits(y3)};
      *(u16x4*)((bf16*)y + base + 4 * i) = pk;
    }
  }
}

// ---------------- orchestration ----------------
extern "C" void kernel_launch(void* const* d_in, const int* in_sizes, int n_in,
                              void* d_out, int out_size, void* d_ws, size_t ws_size,
                              hipStream_t stream) {
  const float* x   = (const float*)d_in[0];
  const int*  mask = (const int*)d_in[1];
  const float* Wq  = (const float*)d_in[2];
  const float* bq  = (const float*)d_in[3];
  const float* Wk  = (const float*)d_in[4];
  const float* bk_ = (const float*)d_in[5];
  const float* Wv  = (const float*)d_in[6];
  const float* bv  = (const float*)d_in[7];
  const float* Wo  = (const float*)d_in[8];
  const float* bo  = (const float*)d_in[9];
  const float* W1  = (const float*)d_in[10];
  const float* b1  = (const float*)d_in[11];
  const float* W2  = (const float*)d_in[12];
  const float* b2  = (const float*)d_in[13];
  const float* g1  = (const float*)d_in[14];
  const float* be1 = (const float*)d_in[15];
  const float* g2  = (const float*)d_in[16];
  const float* be2 = (const float*)d_in[17];

  char* ws = (char*)d_ws;
  const size_t MB = 1ull << 20;
  bf16*  xb    = (bf16*)(ws + 0);          // 16MB (live until LN1)
  bf16*  Qb    = (bf16*)(ws + 16 * MB);    // 16MB (pre-scaled Q)
  bf16*  Kbuf  = (bf16*)(ws + 32 * MB);    // 16MB
  bf16*  Vt    = (bf16*)(ws + 48 * MB);    // 16MB [B,H,64,S]
  bf16*  Hb    = (bf16*)(ws + 0);          // 64MB FFN hidden (xb..Vt dead)
  bf16*  aproj = (bf16*)(ws + 64 * MB);    // 16MB Wo output
  bf16*  f2o   = (bf16*)(ws + 80 * MB);    // 16MB FFN2 output
  bf16*  Ob    = (bf16*)(ws + 96 * MB);    // 16MB attention output
  uint32_t* mfl = (uint32_t*)(ws + 112 * MB);  // 16B
  bf16*  x1b   = (bf16*)(ws + 128 * MB);   // 16MB LN1 output
  bf16*  Wqkvt = (bf16*)(ws + 144 * MB);   // 6MB [3072,1024]
  bf16*  Wot   = (bf16*)(ws + 150 * MB);   // 2MB
  bf16*  W1t   = (bf16*)(ws + 152 * MB);   // 8MB [4096,1024]
  bf16*  W2t   = (bf16*)(ws + 160 * MB);   // 8MB [1024,4096]

  const int SM4 = 131072, SM2 = 98304;
  hipFuncSetAttribute(reinterpret_cast<const void*>(&k_gemm8<EP_QKV, 2>),
                      hipFuncAttributeMaxDynamicSharedMemorySize, SM2);
  hipFuncSetAttribute(reinterpret_cast<const void*>(&k_gemm8<EP_RELU, 4>),
                      hipFuncAttributeMaxDynamicSharedMemorySize, SM4);
  hipFuncSetAttribute(reinterpret_cast<const void*>(&k_gemm8<EP_O16, 2>),
                      hipFuncAttributeMaxDynamicSharedMemorySize, SM2);

  PrepArgs pp;
  pp.x = x; pp.xb = xb; pp.mask = mask; pp.flags = mfl;
  pp.w1 = W1; pp.w1t = W1t;
  pp.w2 = W2; pp.w2t = W2t;
  pp.wx[0] = Wq; pp.wxt[0] = Wqkvt;
  pp.wx[1] = Wk; pp.wxt[1] = Wqkvt + 1024 * 1024;
  pp.wx[2] = Wv; pp.wxt[2] = Wqkvt + 2 * 1024 * 1024;
  pp.wx[3] = Wo; pp.wxt[3] = Wot;
  k_prep<<<7169, 256, 0, stream>>>(pp);

  // fused QKV: N=3072, BN=128, grid 32x24 = 768 blocks (3 exact rounds)
  k_gemm8<EP_QKV, 2><<<dim3(32, 24), 512, SM2, stream>>>(
      xb, Wqkvt, bq, bk_, bv, Qb, Kbuf, Vt, 3072, 1024);

  k_attn<<<1024, 256, 0, stream>>>(Qb, Kbuf, Vt, mask, mfl, Ob);

  k_gemm8<EP_O16, 2><<<dim3(32, 8), 512, SM2, stream>>>(
      Ob, Wot, bo, nullptr, nullptr, aproj, nullptr, nullptr, 1024, 1024);
  k_add_ln<false><<<MROWS / 4, 256, 0, stream>>>(xb, aproj, g1, be1, x1b);

  k_gemm8<EP_RELU, 4><<<dim3(32, 16), 512, SM4, stream>>>(
      x1b, W1t, b1, nullptr, nullptr, Hb, nullptr, nullptr, 4096, 1024);
  k_gemm8<EP_O16, 2><<<dim3(32, 8), 512, SM2, stream>>>(
      Hb, W2t, b2, nullptr, nullptr, f2o, nullptr, nullptr, 1024, 4096);
  k_add_ln<true><<<MROWS / 4, 256, 0, stream>>>(x1b, f2o, g2, be2, (float*)d_out);
}

// Round 15
// 322.682 us; speedup vs baseline: 1.0300x; 1.0174x over previous
//
#include <hip/hip_runtime.h>
#include <hip/hip_bf16.h>
#include <cstdint>
#include <cstddef>

typedef __bf16 bf16;
typedef __bf16 bf16x8 __attribute__((ext_vector_type(8)));
typedef float  f32x4  __attribute__((ext_vector_type(4)));
typedef unsigned short u16x4 __attribute__((ext_vector_type(4)));
typedef uint32_t u32x4 __attribute__((ext_vector_type(4)));

static constexpr int D_MODEL = 1024;
static constexpr int HEADS   = 16;
static constexpr int D_KH    = 64;
static constexpr int D_FF    = 4096;
static constexpr int BATCH   = 4;
static constexpr int SEQ     = 2048;
static constexpr int MROWS   = BATCH * SEQ;  // 8192
static constexpr float QSCALE = 0.18033688011f;  // (1/sqrt(64)) * log2(e)

#define VMCNT(n) asm volatile("s_waitcnt vmcnt(" #n ")" ::: "memory")
#define LGKM0()                                            \
  do {                                                     \
    asm volatile("s_waitcnt lgkmcnt(0)" ::: "memory");     \
    __builtin_amdgcn_sched_barrier(0);                     \
  } while (0)

__device__ __forceinline__ unsigned short bfbits(float f) {
  return __builtin_bit_cast(unsigned short, (bf16)f);
}
__device__ __forceinline__ float bf2f(unsigned short u) {
  return __builtin_bit_cast(float, (uint32_t)u << 16);
}
__device__ __forceinline__ float bf2f_hi(uint32_t w) {
  return __builtin_bit_cast(float, w & 0xffff0000u);
}
__device__ __forceinline__ float bf2f_lo(uint32_t w) {
  return __builtin_bit_cast(float, w << 16);
}
// raw HW exp2 (inputs bounded; no denormal fixup needed)
__device__ __forceinline__ float exp2_raw(float x) {
  float r;
  asm("v_exp_f32 %0, %1" : "=v"(r) : "v"(x));
  return r;
}

__device__ __forceinline__ void gload_lds16(const void* g, void* l) {
  __builtin_amdgcn_global_load_lds(
      (__attribute__((address_space(1))) uint32_t*)(uintptr_t)g,
      (__attribute__((address_space(3))) uint32_t*)(uintptr_t)l, 16, 0, 0);
}

// -------- one prep kernel: x cast (0..4095), mask flags (4096),
//          all weight transposes (4097..7168), vectorized both sides ----
struct PrepArgs {
  const float* x; bf16* xb;
  const int* mask; uint32_t* flags;
  const float* w1; const float* w2; const float* wx[4];
  bf16* w1t; bf16* w2t; bf16* wxt[4];
};
__global__ void k_prep(PrepArgs p) {
  __shared__ float tile[64][65];
  const int t = blockIdx.x;
  if (t < 4096) {
    int i = (t * 256 + threadIdx.x) * 8;
    const float4* q = (const float4*)(p.x + i);
    float4 a = q[0], b = q[1];
    bf16x8 v;
    v[0] = (bf16)a.x; v[1] = (bf16)a.y; v[2] = (bf16)a.z; v[3] = (bf16)a.w;
    v[4] = (bf16)b.x; v[5] = (bf16)b.y; v[6] = (bf16)b.z; v[7] = (bf16)b.w;
    *(bf16x8*)(p.xb + i) = v;
    return;
  }
  if (t == 4096) {
    __shared__ uint32_t sb[4];
    int tid = threadIdx.x;
    if (tid < 4) sb[tid] = 0;
    __syncthreads();
    if (tid < 128) {
      int b = tid >> 5, tt = tid & 31;
      const int4* q = (const int4*)(p.mask + b * SEQ + tt * 64);
      int all = 1;
#pragma unroll
      for (int i = 0; i < 16; ++i) {
        int4 v = q[i];
        all &= v.x & v.y & v.z & v.w;
      }
      if (all) atomicOr(&sb[b], 1u << tt);
    }
    __syncthreads();
    if (tid < 4) p.flags[tid] = sb[tid];
    return;
  }
  // transpose tiles (64x64), float4 loads + u16x4 packed stores
  int u = t - 4097;
  const float* W;
  bf16* Wt;
  int K, N, k0, n0;
  if (u < 1024) {
    W = p.w1; Wt = p.w1t; K = 1024; N = 4096;
    k0 = (u & 15) * 64; n0 = (u >> 4) * 64;
  } else if (u < 2048) {
    int v = u - 1024;
    W = p.w2; Wt = p.w2t; K = 4096; N = 1024;
    k0 = (v & 63) * 64; n0 = (v >> 6) * 64;
  } else {
    int v = u - 2048;
    int which = v >> 8, vv = v & 255;
    W = p.wx[which]; Wt = p.wxt[which]; K = 1024; N = 1024;
    k0 = (vv & 15) * 64; n0 = (vv >> 4) * 64;
  }
  const int c4 = threadIdx.x & 15, r0 = threadIdx.x >> 4;  // 16 f4-cols, 16 rows
#pragma unroll
  for (int i = 0; i < 4; ++i) {
    int r = r0 + i * 16;
    float4 v = *(const float4*)&W[(size_t)(k0 + r) * N + n0 + c4 * 4];
    tile[r][c4 * 4 + 0] = v.x;
    tile[r][c4 * 4 + 1] = v.y;
    tile[r][c4 * 4 + 2] = v.z;
    tile[r][c4 * 4 + 3] = v.w;
  }
  __syncthreads();
  const int ch = threadIdx.x & 15;   // k-chunk of 4 (16 lanes = 128B contiguous)
#pragma unroll
  for (int i = 0; i < 4; ++i) {
    int rr = (threadIdx.x >> 4) + i * 16;  // output row (n-dim)
    u16x4 pk = {bfbits(tile[ch * 4 + 0][rr]), bfbits(tile[ch * 4 + 1][rr]),
                bfbits(tile[ch * 4 + 2][rr]), bfbits(tile[ch * 4 + 3][rr])};
    *(u16x4*)&Wt[(size_t)(n0 + rr) * K + k0 + ch * 4] = pk;
  }
}

// ---------------- GEMM 8-phase: C[M,N] = A[M,K] @ Bt[N,K]^T + bias -------
// BM=256, BN=NREP*64; 8 waves (2M x 4N), per-wave 128 x NREP*16.
enum { EP_RELU = 0, EP_O16 = 1, EP_QKV = 2 };

template <int EPI, int NREP>
__global__ __launch_bounds__(512, 2) void k_gemm8(
    const bf16* __restrict__ A, const bf16* __restrict__ Bt,
    const float* __restrict__ bias, const float* __restrict__ bias2,
    const float* __restrict__ bias3,
    void* __restrict__ Cout, void* __restrict__ C2, void* __restrict__ C3,
    int N, int K) {
  extern __shared__ char smem[];
  constexpr int BN = NREP * 64;
  constexpr int HB = NREP / 2;  // B half-tiles per K-tile (2 or 1)
  const int tid = threadIdx.x;
  const int lane = tid & 63;
  const int wid = tid >> 6;
  const int wm = wid >> 2, wn = wid & 3;
  const int l15 = lane & 15, l4 = lane >> 4;
  const int bx = blockIdx.x, by = blockIdx.y;
  const int NI = K >> 7;  // iters of 2 K-tiles (K % 128 == 0)

  const int c0 = tid, c1 = tid + 512;
  const bf16* baseA0 = A + (size_t)(bx * 256 + (c0 >> 3)) * K + ((c0 & 7) ^ ((c0 >> 3) & 7)) * 8;
  const bf16* baseA1 = A + (size_t)(bx * 256 + (c1 >> 3)) * K + ((c1 & 7) ^ ((c1 >> 3) & 7)) * 8;
  const bf16* baseB0 = Bt + (size_t)(by * BN + (c0 >> 3)) * K + ((c0 & 7) ^ ((c0 >> 3) & 7)) * 8;
  const bf16* baseB1 = Bt + (size_t)(by * BN + (c1 >> 3)) * K + ((c1 & 7) ^ ((c1 >> 3) & 7)) * 8;
  const size_t rowK128 = (size_t)128 * K;

  auto stA = [&](int h, int t, int buf) {
    gload_lds16(baseA0 + h * rowK128 + t * 64, smem + buf * 32768 + h * 16384 + c0 * 16);
    gload_lds16(baseA1 + h * rowK128 + t * 64, smem + buf * 32768 + h * 16384 + c1 * 16);
  };
  auto stB = [&](int h, int t, int buf) {
    gload_lds16(baseB0 + h * rowK128 + t * 64,
                smem + 65536 + buf * (HB * 16384) + h * 16384 + c0 * 16);
    gload_lds16(baseB1 + h * rowK128 + t * 64,
                smem + 65536 + buf * (HB * 16384) + h * 16384 + c1 * 16);
  };

  const int ch0 = (l4 ^ (l15 & 7)) * 16;
  const int ch1 = ((4 + l4) ^ (l15 & 7)) * 16;
  const int aoff = l15 * 128;
  int boffh[NREP];
#pragma unroll
  for (int n = 0; n < NREP; ++n) {
    int rB = wn * (NREP * 16) + n * 16 + l15;
    boffh[n] = (rB >> 7) * 16384 + (rB & 127) * 128;
  }

  f32x4 acc[8][NREP] = {};
  bf16x8 breg[NREP][2];

  // prologue: tile0 -> buf0, tile1 -> buf1
  stA(0, 0, 0); stA(1, 0, 0); stB(0, 0, 0);
  if constexpr (HB == 2) stB(1, 0, 0);
  stA(0, 1, 1); stA(1, 1, 1); stB(0, 1, 1);
  if constexpr (HB == 2) stB(1, 1, 1);

  for (int i = 0; i < NI; ++i) {
    const int t1 = 2 * i + 1, t2 = 2 * i + 2;
    const bool notfirst = (i > 0), notlast = (i + 1 < NI);
#pragma unroll
    for (int p = 0; p < 8; ++p) {
      const int q = p & 3;
      const char* Ab = smem + (p >> 2) * 32768 + wm * 16384;
      const char* Bb = smem + 65536 + (p >> 2) * (HB * 16384);
      if (p == 0) {
        if (notfirst) {
          stA(0, t1, 1);
          VMCNT(2);
        } else {
          if constexpr (HB == 2) VMCNT(8); else VMCNT(6);
        }
        __builtin_amdgcn_s_barrier();
      } else if (p == 4) {
        if (notlast) {
          stA(0, t2, 0);
          VMCNT(2);
        } else {
          VMCNT(0);
        }
        __builtin_amdgcn_s_barrier();
      }
      if (q == 0) {
#pragma unroll
        for (int n = 0; n < NREP; ++n) {
          breg[n][0] = *(const bf16x8*)(Bb + boffh[n] + ch0);
          breg[n][1] = *(const bf16x8*)(Bb + boffh[n] + ch1);
        }
      }
      bf16x8 a0k0 = *(const bf16x8*)(Ab + (2 * q + 0) * 2048 + aoff + ch0);
      bf16x8 a0k1 = *(const bf16x8*)(Ab + (2 * q + 0) * 2048 + aoff + ch1);
      bf16x8 a1k0 = *(const bf16x8*)(Ab + (2 * q + 1) * 2048 + aoff + ch0);
      bf16x8 a1k1 = *(const bf16x8*)(Ab + (2 * q + 1) * 2048 + aoff + ch1);
      if (p == 1) { if (notfirst) stA(1, t1, 1); }
      else if (p == 2) { if (notfirst) stB(0, t1, 1); }
      else if (p == 3) { if constexpr (HB == 2) { if (notfirst) stB(1, t1, 1); } }
      else if (p == 5) { if (notlast) stA(1, t2, 0); }
      else if (p == 6) { if (notlast) stB(0, t2, 0); }
      else if (p == 7) { if constexpr (HB == 2) { if (notlast) stB(1, t2, 0); } }
      if (p != 0 && p != 4) __builtin_amdgcn_s_barrier();
      LGKM0();
      __builtin_amdgcn_s_setprio(1);
#pragma unroll
      for (int n = 0; n < NREP; ++n) {
        acc[2 * q + 0][n] = __builtin_amdgcn_mfma_f32_16x16x32_bf16(a0k0, breg[n][0], acc[2 * q + 0][n], 0, 0, 0);
        acc[2 * q + 0][n] = __builtin_amdgcn_mfma_f32_16x16x32_bf16(a0k1, breg[n][1], acc[2 * q + 0][n], 0, 0, 0);
        acc[2 * q + 1][n] = __builtin_amdgcn_mfma_f32_16x16x32_bf16(a1k0, breg[n][0], acc[2 * q + 1][n], 0, 0, 0);
        acc[2 * q + 1][n] = __builtin_amdgcn_mfma_f32_16x16x32_bf16(a1k1, breg[n][1], acc[2 * q + 1][n], 0, 0, 0);
      }
      __builtin_amdgcn_s_setprio(0);
      __builtin_amdgcn_s_barrier();
    }
  }

  // ---- epilogue ----
  constexpr int BPM = 1024 / BN;  // blocks per matrix (QKV decode)
  float bia[NREP];
#pragma unroll
  for (int n = 0; n < NREP; ++n) {
    int colL = wn * (NREP * 16) + n * 16 + l15;
    if constexpr (EPI == EP_QKV) {
      const int g = by / BPM;
      const float* bp = (g == 0) ? bias : (g == 1 ? bias2 : bias3);
      bia[n] = bp[(by % BPM) * BN + colL];
    } else {
      bia[n] = bias[by * BN + colL];
    }
  }
#pragma unroll
  for (int mf = 0; mf < 8; ++mf) {
    int row0 = bx * 256 + wm * 128 + mf * 16 + l4 * 4;
#pragma unroll
    for (int n = 0; n < NREP; ++n) {
      int colL = wn * (NREP * 16) + n * 16 + l15;
      if constexpr (EPI == EP_QKV) {
        const int g = by / BPM;
        int cc = (by % BPM) * BN + colL;
        if (g == 2) {
          int bidx = row0 >> 11, s0 = row0 & 2047;
          u16x4 pk;
#pragma unroll
          for (int r = 0; r < 4; ++r) pk[r] = bfbits(acc[mf][n][r] + bia[n]);
          *(u16x4*)((bf16*)C3 + (((size_t)bidx * HEADS + (cc >> 6)) * D_KH + (cc & 63)) * SEQ + s0) = pk;
        } else if (g == 0) {
          // Q pre-scaled by QSCALE (softmax scale folded in)
          bf16* dst = (bf16*)Cout;
#pragma unroll
          for (int r = 0; r < 4; ++r)
            dst[(size_t)(row0 + r) * 1024 + cc] = (bf16)((acc[mf][n][r] + bia[n]) * QSCALE);
        } else {
          bf16* dst = (bf16*)C2;
#pragma unroll
          for (int r = 0; r < 4; ++r)
            dst[(size_t)(row0 + r) * 1024 + cc] = (bf16)(acc[mf][n][r] + bia[n]);
        }
      } else {
        int col = by * BN + colL;
#pragma unroll
        for (int r = 0; r < 4; ++r) {
          float v = acc[mf][n][r] + bia[n];
          if constexpr (EPI == EP_RELU) v = fmaxf(v, 0.f);
          ((bf16*)Cout)[(size_t)(row0 + r) * N + col] = (bf16)v;
        }
      }
    }
  }
}

// ---------------- flash attention v11: 64 q-rows / wave -----------------
// grid 512 (XCD-grouped); 4 waves x 64 q-rows = 256 q-rows/block.
// Halves per-CU LDS ds_read redundancy (the dominant pipe at R12: ~41us
// of b128 reads, since K/V fragment addresses are wave-invariant).
// V fragments hoisted to regs once per tile, reused by all 4 m-frags.
__global__ __launch_bounds__(256, 2) void k_attn(
    const bf16* __restrict__ Q, const bf16* __restrict__ Kb,
    const bf16* __restrict__ Vt, const int* __restrict__ mask,
    const uint32_t* __restrict__ Mf, bf16* __restrict__ O) {
  __shared__ bf16 Ks[2][64 * 64];
  __shared__ bf16 Vs[2][64 * 64];
  const int tid = threadIdx.x;
  const int lane = tid & 63;
  const int l15 = lane & 15, l4 = lane >> 4;
  // decode XCD-grouped block id: L = xcd + 8*(qx + 8*yhi), bh = 8*yhi + xcd
  const int L = blockIdx.x;
  const int xcd = L & 7, rest = L >> 3;
  const int qx = rest & 7, yhi = rest >> 3;
  const int bh = yhi * 8 + xcd;
  const int b = bh >> 4, h = bh & 15;
  const size_t qrow0 = (size_t)b * SEQ + qx * 256 + (tid >> 6) * 64;
  const bf16* Kbase = Kb + (size_t)b * SEQ * D_MODEL + h * 64;
  const bf16* Vbase = Vt + (size_t)bh * D_KH * SEQ;
  const int* mbase = mask + b * SEQ;
  const uint32_t mflags = Mf[b];

  bf16x8 qf[4][2];
#pragma unroll
  for (int m = 0; m < 4; ++m)
#pragma unroll
    for (int ks = 0; ks < 2; ++ks)
      qf[m][ks] = *(const bf16x8*)&Q[(qrow0 + m * 16 + l15) * D_MODEL + h * 64 + ks * 32 + l4 * 8];

  f32x4 o[4][4] = {};
  f32x4 rs[4] = {};  // per-lane row sums (rows q = m*16 + l4*4 + r)
  bf16x8 ones;
#pragma unroll
  for (int i = 0; i < 8; ++i) ones[i] = (bf16)1.0f;

  // loop-invariant swizzled LDS read offsets (shared by K and V reads)
  const int koff0 = l15 * 64 + ((l4 * 8) ^ ((l15 & 7) << 3));
  const int koff1 = l15 * 64 + ((32 + l4 * 8) ^ ((l15 & 7) << 3));

  // hoisted staging pointers (advance by constants per tile)
  const int r0_ = tid >> 3, c0_ = (tid & 7) ^ (r0_ & 7);
  const int o1_ = tid + 256;
  const int r1_ = o1_ >> 3, c1_ = (o1_ & 7) ^ (r1_ & 7);
  const bf16* gK0 = Kbase + (size_t)r0_ * D_MODEL + c0_ * 8;
  const bf16* gK1 = Kbase + (size_t)r1_ * D_MODEL + c1_ * 8;
  const bf16* gV0 = Vbase + (size_t)r0_ * SEQ + c0_ * 8;
  const bf16* gV1 = Vbase + (size_t)r1_ * SEQ + c1_ * 8;
  char* ldsK = (char*)&Ks[0][0] + tid * 16;
  char* ldsV = (char*)&Vs[0][0] + tid * 16;

  auto stage = [&](int buf) {
    gload_lds16(gK0, ldsK + buf * 8192);
    gload_lds16(gK1, ldsK + buf * 8192 + 4096);
    gload_lds16(gV0, ldsV + buf * 8192);
    gload_lds16(gV1, ldsV + buf * 8192 + 4096);
    gK0 += 64 * D_MODEL; gK1 += 64 * D_MODEL;
    gV0 += 64; gV1 += 64;
  };

  stage(0);
  __syncthreads();

  for (int kv0 = 0; kv0 < SEQ; kv0 += 64) {
    const int cur = (kv0 >> 6) & 1;
    if (kv0 + 64 < SEQ) stage(cur ^ 1);
    const bf16* Kc = &Ks[cur][0];
    const bf16* Vc = &Vs[cur][0];

    // S^T = K @ Q^T : sf[m][n][r] = S[kv = n*16+l4*4+r][q = m*16+l15]
    f32x4 sf[4][4] = {};
    __builtin_amdgcn_s_setprio(1);
#pragma unroll
    for (int ks = 0; ks < 2; ++ks)
#pragma unroll
      for (int n = 0; n < 4; ++n) {
        bf16x8 kf = *(const bf16x8*)&Kc[(ks ? koff1 : koff0) + n * 1024];
#pragma unroll
        for (int m = 0; m < 4; ++m)
          sf[m][n] = __builtin_amdgcn_mfma_f32_16x16x32_bf16(kf, qf[m][ks], sf[m][n], 0, 0, 0);
      }
    __builtin_amdgcn_s_setprio(0);

    // mask: per-tile all-ones flag (fast path loads nothing per-lane)
    if (__builtin_expect(!((mflags >> (kv0 >> 6)) & 1), 0)) {
#pragma unroll
      for (int n = 0; n < 4; ++n) {
        int4 mk = *(const int4*)&mbase[kv0 + n * 16 + l4 * 4];
#pragma unroll
        for (int r = 0; r < 4; ++r)
          if (((const int*)&mk)[r] == 0) {
#pragma unroll
            for (int m = 0; m < 4; ++m) sf[m][n][r] = -1e30f;
          }
      }
    }

    // hoist V fragments once (reused by all 4 m-frags)
    bf16x8 vf[2][4];
#pragma unroll
    for (int ks = 0; ks < 2; ++ks)
#pragma unroll
      for (int n = 0; n < 4; ++n)
        vf[ks][n] = *(const bf16x8*)&Vc[(ks ? koff1 : koff0) + n * 1024];

    // per-m: softmax (raw exp2) -> pack -> permlane exchange -> PV + rowsum
#pragma unroll
    for (int m = 0; m < 4; ++m) {
      uint32_t pk[4][2];
#pragma unroll
      for (int n = 0; n < 4; ++n) {
#pragma unroll
        for (int r = 0; r < 4; ++r) sf[m][n][r] = exp2_raw(sf[m][n][r]);
        asm("v_cvt_pk_bf16_f32 %0, %1, %2"
            : "=v"(pk[n][0]) : "v"(sf[m][n][0]), "v"(sf[m][n][1]));
        asm("v_cvt_pk_bf16_f32 %0, %1, %2"
            : "=v"(pk[n][1]) : "v"(sf[m][n][2]), "v"(sf[m][n][3]));
      }
      bf16x8 pa[2];
#pragma unroll
      for (int ks = 0; ks < 2; ++ks) {
        u32x4 w;
#pragma unroll
        for (int hh = 0; hh < 2; ++hh) {
          uint32_t a = pk[ks * 2 + 0][hh];
          uint32_t bsw = pk[ks * 2 + 1][hh];
          asm("v_permlane32_swap_b32 %0, %1" : "+v"(a), "+v"(bsw));
          asm("v_permlane16_swap_b32 %0, %1" : "+v"(a), "+v"(bsw));
          w[hh] = a;
          w[2 + hh] = bsw;
        }
        pa[ks] = __builtin_bit_cast(bf16x8, w);
      }
      __builtin_amdgcn_s_setprio(1);
#pragma unroll
      for (int ks = 0; ks < 2; ++ks) {
#pragma unroll
        for (int n = 0; n < 4; ++n)
          o[m][n] = __builtin_amdgcn_mfma_f32_16x16x32_bf16(pa[ks], vf[ks][n], o[m][n], 0, 0, 0);
        rs[m] = __builtin_amdgcn_mfma_f32_16x16x32_bf16(pa[ks], ones, rs[m], 0, 0, 0);
      }
      __builtin_amdgcn_s_setprio(0);
    }
    __syncthreads();
  }

  // epilogue: normalize (row sums already per-lane in rs)
#pragma unroll
  for (int m = 0; m < 4; ++m) {
    float inv[4];
#pragma unroll
    for (int r = 0; r < 4; ++r) inv[r] = 1.0f / rs[m][r];
#pragma unroll
    for (int n = 0; n < 4; ++n)
#pragma unroll
      for (int r = 0; r < 4; ++r)
        O[(qrow0 + m * 16 + l4 * 4 + r) * D_MODEL + h * 64 + n * 16 + l15] =
            (bf16)(o[m][n][r] * inv[r]);
  }
}

// ------- fused residual add + LayerNorm, wave-per-row (no barrier/LDS) ---
template <bool F32OUT>
__global__ __launch_bounds__(256) void k_add_ln(
    const bf16* __restrict__ a, const bf16* __restrict__ b,
    const float* __restrict__ g, const float* __restrict__ be,
    void* __restrict__ y) {
  const int lane = threadIdx.x & 63;
  const size_t row = (size_t)blockIdx.x * 4 + (threadIdx.x >> 6);
  const size_t base = row * D_MODEL + lane * 16;
  uint4 a0 = *(const uint4*)(a + base);
  uint4 a1 = *(const uint4*)(a + base + 8);
  uint4 b0 = *(const uint4*)(b + base);
  uint4 b1 = *(const uint4*)(b + base + 8);
  float v[16];
  const uint32_t* pa0 = (const uint32_t*)&a0;
  const uint32_t* pb0 = (const uint32_t*)&b0;
  const uint32_t* pa1 = (const uint32_t*)&a1;
  const uint32_t* pb1 = (const uint32_t*)&b1;
#pragma unroll
  for (int i = 0; i < 4; ++i) {
    v[2 * i + 0] = bf2f_lo(pa0[i]) + bf2f_lo(pb0[i]);
    v[2 * i + 1] = bf2f_hi(pa0[i]) + bf2f_hi(pb0[i]);
    v[8 + 2 * i + 0] = bf2f_lo(pa1[i]) + bf2f_lo(pb1[i]);
    v[8 + 2 * i + 1] = bf2f_hi(pa1[i]) + bf2f_hi(pb1[i]);
  }
  float s = 0.f, s2 = 0.f;
#pragma unroll
  for (int i = 0; i < 16; ++i) {
    s += v[i];
    s2 = fmaf(v[i], v[i], s2);
  }
#pragma unroll
  for (int off = 1; off < 64; off <<= 1) {
    s  += __shfl_xor(s, off);
    s2 += __shfl_xor(s2, off);
  }
  float mu  = s * (1.f / D_MODEL);
  float var = s2 * (1.f / D_MODEL) - mu * mu;
  float rstd = rsqrtf(var + 1e-5f);
  const float4* gp = (const float4*)(g + lane * 16);
  const float4* bp = (const float4*)(be + lane * 16);
#pragma unroll
  for (int i = 0; i < 4; ++i) {
    float4 gg = gp[i], bb = bp[i];
    float y0 = (v[4 * i + 0] - mu) * rstd * gg.x + bb.x;
    float y1 = (v[4 * i + 1] - mu) * rstd * gg.y + bb.y;
    float y2 = (v[4 * i + 2] - mu) * rstd * gg.z + bb.z;
    float y3 = (v[4 * i + 3] - mu) * rstd * gg.w + bb.w;
    if constexpr (F32OUT) {
      *(float4*)((float*)y + base + 4 * i) = make_float4(y0, y1, y2, y3);
    } else {
      u16x4 pk = {bfbits(y0), bfbits(y1), bfbits(y2), bfbits(y3)};
      *(u16x4*)((bf16*)y + base + 4 * i) = pk;
    }
  }
}

// ---------------- orchestration ----------------
extern "C" void kernel_launch(void* const* d_in, const int* in_sizes, int n_in,
                              void* d_out, int out_size, void* d_ws, size_t ws_size,
                              hipStream_t stream) {
  const float* x   = (const float*)d_in[0];
  const int*  mask = (const int*)d_in[1];
  const float* Wq  = (const float*)d_in[2];
  const float* bq  = (const float*)d_in[3];
  const float* Wk  = (const float*)d_in[4];
  const float* bk_ = (const float*)d_in[5];
  const float* Wv  = (const float*)d_in[6];
  const float* bv  = (const float*)d_in[7];
  const float* Wo  = (const float*)d_in[8];
  const float* bo  = (const float*)d_in[9];
  const float* W1  = (const float*)d_in[10];
  const float* b1  = (const float*)d_in[11];
  const float* W2  = (const float*)d_in[12];
  const float* b2  = (const float*)d_in[13];
  const float* g1  = (const float*)d_in[14];
  const float* be1 = (const float*)d_in[15];
  const float* g2  = (const float*)d_in[16];
  const float* be2 = (const float*)d_in[17];

  char* ws = (char*)d_ws;
  const size_t MB = 1ull << 20;
  bf16*  xb    = (bf16*)(ws + 0);          // 16MB (live until LN1)
  bf16*  Qb    = (bf16*)(ws + 16 * MB);    // 16MB (pre-scaled Q)
  bf16*  Kbuf  = (bf16*)(ws + 32 * MB);    // 16MB
  bf16*  Vt    = (bf16*)(ws + 48 * MB);    // 16MB [B,H,64,S]
  bf16*  Hb    = (bf16*)(ws + 0);          // 64MB FFN hidden (xb..Vt dead)
  bf16*  aproj = (bf16*)(ws + 64 * MB);    // 16MB Wo output
  bf16*  f2o   = (bf16*)(ws + 80 * MB);    // 16MB FFN2 output
  bf16*  Ob    = (bf16*)(ws + 96 * MB);    // 16MB attention output
  uint32_t* mfl = (uint32_t*)(ws + 112 * MB);  // 16B
  bf16*  x1b   = (bf16*)(ws + 128 * MB);   // 16MB LN1 output
  bf16*  Wqkvt = (bf16*)(ws + 144 * MB);   // 6MB [3072,1024]
  bf16*  Wot   = (bf16*)(ws + 150 * MB);   // 2MB
  bf16*  W1t   = (bf16*)(ws + 152 * MB);   // 8MB [4096,1024]
  bf16*  W2t   = (bf16*)(ws + 160 * MB);   // 8MB [1024,4096]

  const int SM4 = 131072, SM2 = 98304;
  hipFuncSetAttribute(reinterpret_cast<const void*>(&k_gemm8<EP_QKV, 2>),
                      hipFuncAttributeMaxDynamicSharedMemorySize, SM2);
  hipFuncSetAttribute(reinterpret_cast<const void*>(&k_gemm8<EP_RELU, 4>),
                      hipFuncAttributeMaxDynamicSharedMemorySize, SM4);
  hipFuncSetAttribute(reinterpret_cast<const void*>(&k_gemm8<EP_O16, 2>),
                      hipFuncAttributeMaxDynamicSharedMemorySize, SM2);

  PrepArgs pp;
  pp.x = x; pp.xb = xb; pp.mask = mask; pp.flags = mfl;
  pp.w1 = W1; pp.w1t = W1t;
  pp.w2 = W2; pp.w2t = W2t;
  pp.wx[0] = Wq; pp.wxt[0] = Wqkvt;
  pp.wx[1] = Wk; pp.wxt[1] = Wqkvt + 1024 * 1024;
  pp.wx[2] = Wv; pp.wxt[2] = Wqkvt + 2 * 1024 * 1024;
  pp.wx[3] = Wo; pp.wxt[3] = Wot;
  k_prep<<<7169, 256, 0, stream>>>(pp);

  // fused QKV: N=3072, BN=128, grid 32x24 = 768 blocks (3 exact rounds)
  k_gemm8<EP_QKV, 2><<<dim3(32, 24), 512, SM2, stream>>>(
      xb, Wqkvt, bq, bk_, bv, Qb, Kbuf, Vt, 3072, 1024);

  k_attn<<<512, 256, 0, stream>>>(Qb, Kbuf, Vt, mask, mfl, Ob);

  k_gemm8<EP_O16, 2><<<dim3(32, 8), 512, SM2, stream>>>(
      Ob, Wot, bo, nullptr, nullptr, aproj, nullptr, nullptr, 1024, 1024);
  k_add_ln<false><<<MROWS / 4, 256, 0, stream>>>(xb, aproj, g1, be1, x1b);

  k_gemm8<EP_RELU, 4><<<dim3(32, 16), 512, SM4, stream>>>(
      x1b, W1t, b1, nullptr, nullptr, Hb, nullptr, nullptr, 4096, 1024);
  k_gemm8<EP_O16, 2><<<dim3(32, 8), 512, SM2, stream>>>(
      Hb, W2t, b2, nullptr, nullptr, f2o, nullptr, nullptr, 1024, 4096);
  k_add_ln<true><<<MROWS / 4, 256, 0, stream>>>(x1b, f2o, g2, be2, (float*)d_out);
}